// Round 5
// baseline (597.236 us; speedup 1.0000x reference)
//
#include <hip/hip_runtime.h>

// Problem: B=4, S=2048, H=16, D=64, E=1024. Inputs fp32, output fp32.
// out = proj( attention( cos(x+theta) ) )  with Q==K==V per head.
//
// Round 5: hoist cos into a one-time qkv kernel (bf16 qkv + qkvT in ws),
// attention loads all MFMA fragments DIRECTLY from global (L1/L2-resident),
// no K/V LDS staging, no __syncthreads in the K-loop. P round-trips through
// per-wave LDS with lgkmcnt(0).
// ws layout: [0,16M) qkv  [16M,32M) qkvT  [32M,48M) aout (bf16).

#define B_  4
#define S_  2048
#define H_  16
#define D_  64
#define E_  1024
#define SCALE 0.125f  // 1/sqrt(64)

typedef unsigned short u16;
typedef __attribute__((ext_vector_type(8))) short short8;
typedef __attribute__((ext_vector_type(4))) float floatx4;

static __device__ __forceinline__ float bf2f(u16 v) {
    return __uint_as_float(((unsigned)v) << 16);
}
static __device__ __forceinline__ u16 f2bf(float f) {
    unsigned u = __float_as_uint(f);
    return (u16)((u + 0x7FFFu + ((u >> 16) & 1u)) >> 16);
}

// ---------------------------------------------------------------------------
// Kernel 1: qkv[bh][s][d] = cos(x[b][s][h*64+d] + theta[h][d])   (bf16)
//           qkvT[bh][d][s] = transpose                            (bf16)
// 2048 blocks x 256 threads; each block: one (bh, 64-row s-tile).
// ---------------------------------------------------------------------------
__global__ __launch_bounds__(256) void qkv_kernel(const float* __restrict__ x,
                                                  const float* __restrict__ theta,
                                                  u16* __restrict__ qkv,
                                                  u16* __restrict__ qkvT) {
    int blk   = blockIdx.x;
    int stile = blk & 31;
    int bh    = blk >> 5;
    int b     = bh >> 4;
    int h     = bh & 15;
    int tid   = threadIdx.x;
    int i     = tid >> 2;          // s row in tile
    int d0    = (tid & 3) << 4;    // 16 dims
    int s0    = stile << 6;
    int s     = s0 + i;

    __shared__ __align__(16) u16 TQ[64][72];   // [d][s_local]

    const float* xp = x + ((size_t)(b * S_ + s)) * E_ + h * D_ + d0;
    const float* tp = theta + h * D_ + d0;

    u16 ov[16];
#pragma unroll
    for (int j = 0; j < 16; j += 4) {
        float4 xv = *(const float4*)(xp + j);
        float4 tv = *(const float4*)(tp + j);
        ov[j]     = f2bf(__cosf(xv.x + tv.x));
        ov[j + 1] = f2bf(__cosf(xv.y + tv.y));
        ov[j + 2] = f2bf(__cosf(xv.z + tv.z));
        ov[j + 3] = f2bf(__cosf(xv.w + tv.w));
    }

    u16* qp = qkv + ((size_t)bh * S_ + s) * D_ + d0;
    *(uint4*)qp       = *(uint4*)&ov[0];
    *(uint4*)(qp + 8) = *(uint4*)&ov[8];

#pragma unroll
    for (int j = 0; j < 16; j++) TQ[d0 + j][i] = ov[j];
    __syncthreads();

    int d  = tid >> 2;
    int j0 = (tid & 3) << 4;
    u16 tmp[16];
#pragma unroll
    for (int j = 0; j < 16; j++) tmp[j] = TQ[d][j0 + j];
    u16* qtp = qkvT + ((size_t)bh * D_ + d) * S_ + s0 + j0;
    *(uint4*)qtp       = *(uint4*)&tmp[0];
    *(uint4*)(qtp + 8) = *(uint4*)&tmp[8];
}

// ---------------------------------------------------------------------------
// Kernel 2: flash attention per (bh, q-tile of 64). 4 waves; wave w owns q
// rows [w*16,w*16+16). All MFMA fragments loaded directly from global
// (qkv rows for Q/K, qkvT rows for V). Only P round-trips through LDS.
// ---------------------------------------------------------------------------
__global__ __launch_bounds__(256) void attn_kernel(const u16* __restrict__ qkv,
                                                   const u16* __restrict__ qkvT,
                                                   u16* __restrict__ aout) {
    int blk  = blockIdx.x;
    int qt   = blk & 31;
    int bh   = blk >> 5;
    int b    = bh >> 4;
    int h    = bh & 15;
    int tid  = threadIdx.x;
    int wave = tid >> 6;
    int lane = tid & 63;
    int lq   = lane & 15;   // A-frag row / C-frag col
    int lg   = lane >> 4;   // group 0..3

    __shared__ __align__(16) u16 Ps[4][16][72];     // per-wave P tile [m][k]

    const u16* base  = qkv  + (size_t)bh * S_ * D_;
    const u16* baseT = qkvT + (size_t)bh * D_ * S_;
    int s0 = qt * 64;

    // Q A-fragments: A[m=lq][k=lg*8+j (+32)] — direct global 16B loads
    const u16* qrow = base + (size_t)(s0 + wave * 16 + lq) * D_ + lg * 8;
    short8 aq0 = *(const short8*)qrow;
    short8 aq1 = *(const short8*)(qrow + 32);

    floatx4 oacc[4] = {{0,0,0,0},{0,0,0,0},{0,0,0,0},{0,0,0,0}};
    float mr[4] = {-1e30f, -1e30f, -1e30f, -1e30f};
    float lr[4] = {0.f, 0.f, 0.f, 0.f};

    for (int kt = 0; kt < S_ / 64; kt++) {
        // S = Q K^T * scale : 4 column tiles of 16 keys; K frags from global
        floatx4 sc[4];
#pragma unroll
        for (int t = 0; t < 4; t++) {
            const u16* krow = base + (size_t)(kt * 64 + t * 16 + lq) * D_ + lg * 8;
            short8 b0 = *(const short8*)krow;
            short8 b1 = *(const short8*)(krow + 32);
            floatx4 acc = {0, 0, 0, 0};
            acc = __builtin_amdgcn_mfma_f32_16x16x32_bf16(aq0, b0, acc, 0, 0, 0);
            acc = __builtin_amdgcn_mfma_f32_16x16x32_bf16(aq1, b1, acc, 0, 0, 0);
#pragma unroll
            for (int rr = 0; rr < 4; rr++) acc[rr] *= SCALE;
            sc[t] = acc;
        }

        // online softmax; row lg*4+rr lives in 16 consecutive lanes
#pragma unroll
        for (int rr = 0; rr < 4; rr++) {
            float mx = fmaxf(fmaxf(sc[0][rr], sc[1][rr]), fmaxf(sc[2][rr], sc[3][rr]));
            mx = fmaxf(mx, __shfl_xor(mx, 1, 16));
            mx = fmaxf(mx, __shfl_xor(mx, 2, 16));
            mx = fmaxf(mx, __shfl_xor(mx, 4, 16));
            mx = fmaxf(mx, __shfl_xor(mx, 8, 16));
            float mnew  = fmaxf(mr[rr], mx);
            float alpha = __expf(mr[rr] - mnew);
            mr[rr] = mnew;
            float ps = 0.f;
#pragma unroll
            for (int t = 0; t < 4; t++) {
                float p = __expf(sc[t][rr] - mnew);
                sc[t][rr] = p;
                ps += p;
            }
            ps += __shfl_xor(ps, 1, 16);
            ps += __shfl_xor(ps, 2, 16);
            ps += __shfl_xor(ps, 4, 16);
            ps += __shfl_xor(ps, 8, 16);
            lr[rr] = lr[rr] * alpha + ps;
#pragma unroll
            for (int t = 0; t < 4; t++) oacc[t][rr] *= alpha;
        }

        // write P (C-layout) to per-wave LDS as [m][k] bf16
#pragma unroll
        for (int t = 0; t < 4; t++)
#pragma unroll
            for (int rr = 0; rr < 4; rr++)
                Ps[wave][lg * 4 + rr][t * 16 + lq] = f2bf(sc[t][rr]);

        // per-wave LDS: DS pipe is in-order per wave; drain writes before reads
        asm volatile("s_waitcnt lgkmcnt(0)" ::: "memory");

        // O += P[16x64] * V[64x64]; V frags from qkvT global rows
        short8 ap0 = *(short8*)&Ps[wave][lq][lg * 8];
        short8 ap1 = *(short8*)&Ps[wave][lq][32 + lg * 8];
#pragma unroll
        for (int t = 0; t < 4; t++) {
            const u16* vrow = baseT + (size_t)(t * 16 + lq) * S_ + kt * 64 + lg * 8;
            short8 bv0 = *(const short8*)vrow;
            short8 bv1 = *(const short8*)(vrow + 32);
            oacc[t] = __builtin_amdgcn_mfma_f32_16x16x32_bf16(ap0, bv0, oacc[t], 0, 0, 0);
            oacc[t] = __builtin_amdgcn_mfma_f32_16x16x32_bf16(ap1, bv1, oacc[t], 0, 0, 0);
        }
    }

    // epilogue: O /= l, write aout[b][s][h*64+col] (bf16 intermediate)
#pragma unroll
    for (int t = 0; t < 4; t++) {
#pragma unroll
        for (int rr = 0; rr < 4; rr++) {
            float inv = 1.0f / fmaxf(lr[rr], 1e-20f);
            int srow = s0 + wave * 16 + lg * 4 + rr;
            int col  = h * D_ + t * 16 + lq;
            aout[((size_t)(b * S_ + srow)) * E_ + col] = f2bf(oacc[t][rr] * inv);
        }
    }
}

// ---------------------------------------------------------------------------
// Kernel 3: out[8192][1024] = AO * W^T + bias (fp32 out). W fp32 [n][k].
// ---------------------------------------------------------------------------
__global__ __launch_bounds__(256) void proj_kernel(const u16* __restrict__ A,
                                                   const float* __restrict__ W,
                                                   const float* __restrict__ bias,
                                                   float* __restrict__ out) {
    int m0   = blockIdx.x * 64;
    int n0   = blockIdx.y * 64;
    int tid  = threadIdx.x;
    int wave = tid >> 6;
    int lane = tid & 63;
    int lq   = lane & 15;
    int lg   = lane >> 4;
    int r    = tid >> 2;
    int c0   = (tid & 3) << 4;

    __shared__ __align__(16) u16 As[64][72];
    __shared__ __align__(16) u16 Bs[64][72];

    floatx4 acc[4] = {{0,0,0,0},{0,0,0,0},{0,0,0,0},{0,0,0,0}};

    for (int kc = 0; kc < E_; kc += 64) {
        __syncthreads();
        const u16* pa = A + (size_t)(m0 + r) * E_ + kc + c0;
        *(uint4*)&As[r][c0]     = *(const uint4*)pa;
        *(uint4*)&As[r][c0 + 8] = *(const uint4*)(pa + 8);
        {
            const float* pw = W + (size_t)(n0 + r) * E_ + kc + c0;
            u16 ov[16];
#pragma unroll
            for (int j = 0; j < 16; j += 4) {
                float4 wv = *(const float4*)(pw + j);
                ov[j]     = f2bf(wv.x);
                ov[j + 1] = f2bf(wv.y);
                ov[j + 2] = f2bf(wv.z);
                ov[j + 3] = f2bf(wv.w);
            }
            *(uint4*)&Bs[r][c0]     = *(uint4*)&ov[0];
            *(uint4*)&Bs[r][c0 + 8] = *(uint4*)&ov[8];
        }
        __syncthreads();

#pragma unroll
        for (int c = 0; c < 2; c++) {
            short8 a = *(short8*)&As[wave * 16 + lq][c * 32 + lg * 8];
#pragma unroll
            for (int t = 0; t < 4; t++) {
                short8 bb = *(short8*)&Bs[t * 16 + lq][c * 32 + lg * 8];
                acc[t] = __builtin_amdgcn_mfma_f32_16x16x32_bf16(a, bb, acc[t], 0, 0, 0);
            }
        }
    }

#pragma unroll
    for (int t = 0; t < 4; t++) {
        int nidx = n0 + t * 16 + lq;
        float bv = bias[nidx];
#pragma unroll
        for (int rr = 0; rr < 4; rr++) {
            int row = m0 + wave * 16 + lg * 4 + rr;
            out[(size_t)row * E_ + nidx] = acc[t][rr] + bv;
        }
    }
}

// ---------------------------------------------------------------------------
extern "C" void kernel_launch(void* const* d_in, const int* in_sizes, int n_in,
                              void* d_out, int out_size, void* d_ws, size_t ws_size,
                              hipStream_t stream) {
    const float* x     = (const float*)d_in[0];
    const float* theta = (const float*)d_in[1];
    const float* w_out = (const float*)d_in[2];
    const float* b_out = (const float*)d_in[3];
    float* out = (float*)d_out;

    char* ws = (char*)d_ws;
    const size_t QKV_BYTES = (size_t)B_ * H_ * S_ * D_ * sizeof(u16);  // 16 MiB
    u16* qkv  = (u16*)ws;
    u16* qkvT = (u16*)(ws + QKV_BYTES);
    u16* aout = (u16*)(ws + 2 * QKV_BYTES);

    qkv_kernel<<<(B_ * H_) * (S_ / 64), 256, 0, stream>>>(x, theta, qkv, qkvT);
    attn_kernel<<<(B_ * H_) * (S_ / 64), 256, 0, stream>>>(qkv, qkvT, aout);
    dim3 pg(B_ * S_ / 64, E_ / 64);
    proj_kernel<<<pg, 256, 0, stream>>>(aout, w_out, b_out, out);
}

// Round 6
// 269.410 us; speedup vs baseline: 2.2168x; 2.2168x over previous
//
#include <hip/hip_runtime.h>

// Problem: B=4, S=2048, H=16, D=64, E=1024. Inputs fp32, output fp32.
// out = proj( attention( cos(x+theta) ) )  with Q==K==V per head.
//
// Round 6: precomputed bf16 qkv/qkvT + LDS-staged K/V tiles (round-4
// structure, conflict-free vector staging) + max-free unnormalized softmax
// (scores bounded by 8, exp safe in fp32) + one-time bf16 W conversion.
// ws: [0,16M) qkv (reused as Wbf after attn)  [16M,32M) qkvT  [32M,48M) aout.

#define B_  4
#define S_  2048
#define H_  16
#define D_  64
#define E_  1024
// exp(s * 1/8) = exp2(s * log2(e)/8)
#define EXP2_SCALE 0.18033688011112043f

typedef unsigned short u16;
typedef __attribute__((ext_vector_type(8))) short short8;
typedef __attribute__((ext_vector_type(4))) float floatx4;

static __device__ __forceinline__ float bf2f(u16 v) {
    return __uint_as_float(((unsigned)v) << 16);
}
static __device__ __forceinline__ u16 f2bf(float f) {
    unsigned u = __float_as_uint(f);
    return (u16)((u + 0x7FFFu + ((u >> 16) & 1u)) >> 16);
}

// ---------------------------------------------------------------------------
// Kernel 1: qkv[bh][s][d] = cos(x[b][s][h*64+d] + theta[h][d])   (bf16)
//           qkvT[bh][d][s] = transpose                            (bf16)
// ---------------------------------------------------------------------------
__global__ __launch_bounds__(256) void qkv_kernel(const float* __restrict__ x,
                                                  const float* __restrict__ theta,
                                                  u16* __restrict__ qkv,
                                                  u16* __restrict__ qkvT) {
    int blk   = blockIdx.x;
    int stile = blk & 31;
    int bh    = blk >> 5;
    int b     = bh >> 4;
    int h     = bh & 15;
    int tid   = threadIdx.x;
    int i     = tid >> 2;
    int d0    = (tid & 3) << 4;
    int s0    = stile << 6;
    int s     = s0 + i;

    __shared__ __align__(16) u16 TQ[64][72];

    const float* xp = x + ((size_t)(b * S_ + s)) * E_ + h * D_ + d0;
    const float* tp = theta + h * D_ + d0;

    u16 ov[16];
#pragma unroll
    for (int j = 0; j < 16; j += 4) {
        float4 xv = *(const float4*)(xp + j);
        float4 tv = *(const float4*)(tp + j);
        ov[j]     = f2bf(__cosf(xv.x + tv.x));
        ov[j + 1] = f2bf(__cosf(xv.y + tv.y));
        ov[j + 2] = f2bf(__cosf(xv.z + tv.z));
        ov[j + 3] = f2bf(__cosf(xv.w + tv.w));
    }

    u16* qp = qkv + ((size_t)bh * S_ + s) * D_ + d0;
    *(uint4*)qp       = *(uint4*)&ov[0];
    *(uint4*)(qp + 8) = *(uint4*)&ov[8];

#pragma unroll
    for (int j = 0; j < 16; j++) TQ[d0 + j][i] = ov[j];
    __syncthreads();

    int d  = tid >> 2;
    int j0 = (tid & 3) << 4;
    u16 tmp[16];
#pragma unroll
    for (int j = 0; j < 16; j++) tmp[j] = TQ[d][j0 + j];
    u16* qtp = qkvT + ((size_t)bh * D_ + d) * S_ + s0 + j0;
    *(uint4*)qtp       = *(uint4*)&tmp[0];
    *(uint4*)(qtp + 8) = *(uint4*)&tmp[8];
}

// ---------------------------------------------------------------------------
// Kernel 2: flash attention per (bh, 64-q-tile). 4 waves; wave w owns q rows
// [w*16,w*16+16). LDS-staged K/V tiles; max-free softmax (scores in [-8,8]).
// ---------------------------------------------------------------------------
__global__ __launch_bounds__(256) void attn_kernel(const u16* __restrict__ qkv,
                                                   const u16* __restrict__ qkvT,
                                                   u16* __restrict__ aout) {
    int blk  = blockIdx.x;
    int qt   = blk & 31;
    int bh   = blk >> 5;
    int b    = bh >> 4;
    int h    = bh & 15;
    int tid  = threadIdx.x;
    int wave = tid >> 6;
    int lane = tid & 63;
    int lq   = lane & 15;   // A-frag row / C-frag col
    int lg   = lane >> 4;   // group 0..3
    int r    = tid >> 2;    // staging row 0..63
    int c0   = (tid & 3) << 4;  // staging col base

    __shared__ __align__(16) u16 Qs[64][72];
    __shared__ __align__(16) u16 Kt[64][72];      // K tile [key][d]
    __shared__ __align__(16) u16 Vt[64][72];      // V^T tile [d][key]
    __shared__ __align__(16) u16 Ps[4][16][72];   // per-wave P tile [m][key]

    const u16* base  = qkv  + (size_t)bh * S_ * D_;
    const u16* baseT = qkvT + (size_t)bh * D_ * S_;
    int s0 = qt * 64;

    // stage Q tile (pure copy, bf16)
    {
        const u16* p = base + (size_t)(s0 + r) * D_ + c0;
        *(uint4*)&Qs[r][c0]     = *(const uint4*)p;
        *(uint4*)&Qs[r][c0 + 8] = *(const uint4*)(p + 8);
    }
    __syncthreads();

    short8 aq0 = *(short8*)&Qs[wave * 16 + lq][lg * 8];
    short8 aq1 = *(short8*)&Qs[wave * 16 + lq][32 + lg * 8];

    floatx4 oacc[4] = {{0,0,0,0},{0,0,0,0},{0,0,0,0},{0,0,0,0}};
    float lr[4] = {0.f, 0.f, 0.f, 0.f};   // lane-partial exp sums

    for (int kt = 0; kt < S_ / 64; kt++) {
        __syncthreads();   // prev iteration's Kt/Vt reads complete
        // stage K tile from qkv and V^T tile from qkvT (vector copies)
        {
            const u16* p = base + (size_t)(kt * 64 + r) * D_ + c0;
            *(uint4*)&Kt[r][c0]     = *(const uint4*)p;
            *(uint4*)&Kt[r][c0 + 8] = *(const uint4*)(p + 8);
            const u16* p2 = baseT + (size_t)r * S_ + kt * 64 + c0;
            *(uint4*)&Vt[r][c0]     = *(const uint4*)p2;
            *(uint4*)&Vt[r][c0 + 8] = *(const uint4*)(p2 + 8);
        }
        __syncthreads();

        // S = Q K^T : 4 column tiles of 16 keys
        floatx4 sc[4];
#pragma unroll
        for (int t = 0; t < 4; t++) {
            floatx4 acc = {0, 0, 0, 0};
            short8 b0 = *(short8*)&Kt[t * 16 + lq][lg * 8];
            acc = __builtin_amdgcn_mfma_f32_16x16x32_bf16(aq0, b0, acc, 0, 0, 0);
            short8 b1 = *(short8*)&Kt[t * 16 + lq][32 + lg * 8];
            acc = __builtin_amdgcn_mfma_f32_16x16x32_bf16(aq1, b1, acc, 0, 0, 0);
            sc[t] = acc;
        }

        // max-free softmax: p = exp(s/8) = exp2(s * EXP2_SCALE); l += p
#pragma unroll
        for (int t = 0; t < 4; t++) {
#pragma unroll
            for (int rr = 0; rr < 4; rr++) {
                float p = exp2f(sc[t][rr] * EXP2_SCALE);
                sc[t][rr] = p;
                lr[rr] += p;
            }
        }

        // write P (C-layout) to per-wave LDS as [m][key] bf16
#pragma unroll
        for (int t = 0; t < 4; t++)
#pragma unroll
            for (int rr = 0; rr < 4; rr++)
                Ps[wave][lg * 4 + rr][t * 16 + lq] = f2bf(sc[t][rr]);

        // per-wave LDS: DS pipe in-order per wave; drain writes before reads
        asm volatile("s_waitcnt lgkmcnt(0)" ::: "memory");

        // O += P[16x64] * V[64x64]
        short8 ap0 = *(short8*)&Ps[wave][lq][lg * 8];
        short8 ap1 = *(short8*)&Ps[wave][lq][32 + lg * 8];
#pragma unroll
        for (int t = 0; t < 4; t++) {
            short8 bv0 = *(short8*)&Vt[t * 16 + lq][lg * 8];
            oacc[t] = __builtin_amdgcn_mfma_f32_16x16x32_bf16(ap0, bv0, oacc[t], 0, 0, 0);
            short8 bv1 = *(short8*)&Vt[t * 16 + lq][32 + lg * 8];
            oacc[t] = __builtin_amdgcn_mfma_f32_16x16x32_bf16(ap1, bv1, oacc[t], 0, 0, 0);
        }
    }

    // reduce row sums across the 16 lanes holding each row, then normalize
#pragma unroll
    for (int rr = 0; rr < 4; rr++) {
        lr[rr] += __shfl_xor(lr[rr], 1, 16);
        lr[rr] += __shfl_xor(lr[rr], 2, 16);
        lr[rr] += __shfl_xor(lr[rr], 4, 16);
        lr[rr] += __shfl_xor(lr[rr], 8, 16);
    }
#pragma unroll
    for (int t = 0; t < 4; t++) {
#pragma unroll
        for (int rr = 0; rr < 4; rr++) {
            float inv = 1.0f / fmaxf(lr[rr], 1e-20f);
            int srow = s0 + wave * 16 + lg * 4 + rr;
            int col  = h * D_ + t * 16 + lq;
            aout[((size_t)(b * S_ + srow)) * E_ + col] = f2bf(oacc[t][rr] * inv);
        }
    }
}

// ---------------------------------------------------------------------------
// Kernel 3: Wbf[i] = bf16(W[i])  — one-time weight conversion (1M elems)
// ---------------------------------------------------------------------------
__global__ __launch_bounds__(256) void wconv_kernel(const float* __restrict__ W,
                                                    u16* __restrict__ Wb) {
    int i = (blockIdx.x * 256 + threadIdx.x) * 4;
    float4 w = *(const float4*)(W + i);
    ushort4 o;
    o.x = f2bf(w.x); o.y = f2bf(w.y); o.z = f2bf(w.z); o.w = f2bf(w.w);
    *(ushort4*)(Wb + i) = o;
}

// ---------------------------------------------------------------------------
// Kernel 4: out[8192][1024] = AO * Wb^T + bias (fp32 out). Wb bf16 [n][k].
// ---------------------------------------------------------------------------
__global__ __launch_bounds__(256) void proj_kernel(const u16* __restrict__ A,
                                                   const u16* __restrict__ Wb,
                                                   const float* __restrict__ bias,
                                                   float* __restrict__ out) {
    int m0   = blockIdx.x * 64;
    int n0   = blockIdx.y * 64;
    int tid  = threadIdx.x;
    int wave = tid >> 6;
    int lane = tid & 63;
    int lq   = lane & 15;
    int lg   = lane >> 4;
    int r    = tid >> 2;
    int c0   = (tid & 3) << 4;

    __shared__ __align__(16) u16 As[64][72];
    __shared__ __align__(16) u16 Bs[64][72];

    floatx4 acc[4] = {{0,0,0,0},{0,0,0,0},{0,0,0,0},{0,0,0,0}};

    for (int kc = 0; kc < E_; kc += 64) {
        __syncthreads();
        const u16* pa = A + (size_t)(m0 + r) * E_ + kc + c0;
        *(uint4*)&As[r][c0]     = *(const uint4*)pa;
        *(uint4*)&As[r][c0 + 8] = *(const uint4*)(pa + 8);
        const u16* pw = Wb + (size_t)(n0 + r) * E_ + kc + c0;
        *(uint4*)&Bs[r][c0]     = *(const uint4*)pw;
        *(uint4*)&Bs[r][c0 + 8] = *(const uint4*)(pw + 8);
        __syncthreads();

#pragma unroll
        for (int c = 0; c < 2; c++) {
            short8 a = *(short8*)&As[wave * 16 + lq][c * 32 + lg * 8];
#pragma unroll
            for (int t = 0; t < 4; t++) {
                short8 bb = *(short8*)&Bs[t * 16 + lq][c * 32 + lg * 8];
                acc[t] = __builtin_amdgcn_mfma_f32_16x16x32_bf16(a, bb, acc[t], 0, 0, 0);
            }
        }
    }

#pragma unroll
    for (int t = 0; t < 4; t++) {
        int nidx = n0 + t * 16 + lq;
        float bv = bias[nidx];
#pragma unroll
        for (int rr = 0; rr < 4; rr++) {
            int row = m0 + wave * 16 + lg * 4 + rr;
            out[(size_t)row * E_ + nidx] = acc[t][rr] + bv;
        }
    }
}

// ---------------------------------------------------------------------------
extern "C" void kernel_launch(void* const* d_in, const int* in_sizes, int n_in,
                              void* d_out, int out_size, void* d_ws, size_t ws_size,
                              hipStream_t stream) {
    const float* x     = (const float*)d_in[0];
    const float* theta = (const float*)d_in[1];
    const float* w_out = (const float*)d_in[2];
    const float* b_out = (const float*)d_in[3];
    float* out = (float*)d_out;

    char* ws = (char*)d_ws;
    const size_t QKV_BYTES = (size_t)B_ * H_ * S_ * D_ * sizeof(u16);  // 16 MiB
    u16* qkv  = (u16*)ws;
    u16* qkvT = (u16*)(ws + QKV_BYTES);
    u16* aout = (u16*)(ws + 2 * QKV_BYTES);
    u16* wbf  = (u16*)ws;   // reuses qkv region AFTER attn completes (stream-ordered)

    qkv_kernel<<<(B_ * H_) * (S_ / 64), 256, 0, stream>>>(x, theta, qkv, qkvT);
    attn_kernel<<<(B_ * H_) * (S_ / 64), 256, 0, stream>>>(qkv, qkvT, aout);
    wconv_kernel<<<(E_ * E_) / 1024, 256, 0, stream>>>(w_out, wbf);
    dim3 pg(B_ * S_ / 64, E_ / 64);
    proj_kernel<<<pg, 256, 0, stream>>>(aout, wbf, b_out, out);
}

// Round 7
// 241.585 us; speedup vs baseline: 2.4722x; 1.1152x over previous
//
#include <hip/hip_runtime.h>

// Problem: B=4, S=2048, H=16, D=64, E=1024. Inputs fp32, output fp32.
// out = proj( attention( cos(x+theta) ) )  with Q==K==V per head.
//
// Round 7: attn q-blocking (128-row q-tile, 32 q-rows/wave => K/V LDS frag
// reads amortized over 2 row-frags, barriers/FLOP halved) + proj 128x128
// tile (m93 pattern). Max-free softmax (scores bounded by 8).
// ws: [0,16M) qkv (reused as Wbf after attn)  [16M,32M) qkvT  [32M,48M) aout.

#define B_  4
#define S_  2048
#define H_  16
#define D_  64
#define E_  1024
// exp(s/8) = exp2(s * log2(e)/8)
#define EXP2_SCALE 0.18033688011112043f

typedef unsigned short u16;
typedef __attribute__((ext_vector_type(8))) short short8;
typedef __attribute__((ext_vector_type(4))) float floatx4;

static __device__ __forceinline__ float bf2f(u16 v) {
    return __uint_as_float(((unsigned)v) << 16);
}
static __device__ __forceinline__ u16 f2bf(float f) {
    unsigned u = __float_as_uint(f);
    return (u16)((u + 0x7FFFu + ((u >> 16) & 1u)) >> 16);
}

// ---------------------------------------------------------------------------
// Kernel 1: qkv[bh][s][d] = cos(x[b][s][h*64+d] + theta[h][d])   (bf16)
//           qkvT[bh][d][s] = transpose                            (bf16)
// ---------------------------------------------------------------------------
__global__ __launch_bounds__(256) void qkv_kernel(const float* __restrict__ x,
                                                  const float* __restrict__ theta,
                                                  u16* __restrict__ qkv,
                                                  u16* __restrict__ qkvT) {
    int blk   = blockIdx.x;
    int stile = blk & 31;
    int bh    = blk >> 5;
    int b     = bh >> 4;
    int h     = bh & 15;
    int tid   = threadIdx.x;
    int i     = tid >> 2;
    int d0    = (tid & 3) << 4;
    int s0    = stile << 6;
    int s     = s0 + i;

    __shared__ __align__(16) u16 TQ[64][72];

    const float* xp = x + ((size_t)(b * S_ + s)) * E_ + h * D_ + d0;
    const float* tp = theta + h * D_ + d0;

    u16 ov[16];
#pragma unroll
    for (int j = 0; j < 16; j += 4) {
        float4 xv = *(const float4*)(xp + j);
        float4 tv = *(const float4*)(tp + j);
        ov[j]     = f2bf(__cosf(xv.x + tv.x));
        ov[j + 1] = f2bf(__cosf(xv.y + tv.y));
        ov[j + 2] = f2bf(__cosf(xv.z + tv.z));
        ov[j + 3] = f2bf(__cosf(xv.w + tv.w));
    }

    u16* qp = qkv + ((size_t)bh * S_ + s) * D_ + d0;
    *(uint4*)qp       = *(uint4*)&ov[0];
    *(uint4*)(qp + 8) = *(uint4*)&ov[8];

#pragma unroll
    for (int j = 0; j < 16; j++) TQ[d0 + j][i] = ov[j];
    __syncthreads();

    int d  = tid >> 2;
    int j0 = (tid & 3) << 4;
    u16 tmp[16];
#pragma unroll
    for (int j = 0; j < 16; j++) tmp[j] = TQ[d][j0 + j];
    u16* qtp = qkvT + ((size_t)bh * D_ + d) * S_ + s0 + j0;
    *(uint4*)qtp       = *(uint4*)&tmp[0];
    *(uint4*)(qtp + 8) = *(uint4*)&tmp[8];
}

// ---------------------------------------------------------------------------
// Kernel 2: flash attention per (bh, 128-q-tile). 4 waves; wave w owns q rows
// [w*32, w*32+32) as 2 row-fragments. K/V LDS tiles shared; B-frags reused
// across both row-frags. Max-free softmax. Q A-frags direct from global
// (loop-invariant). Grid 1024 blocks = 4/CU co-resident.
// ---------------------------------------------------------------------------
__global__ __launch_bounds__(256, 4) void attn_kernel(const u16* __restrict__ qkv,
                                                      const u16* __restrict__ qkvT,
                                                      u16* __restrict__ aout) {
    int blk  = blockIdx.x;
    int qt   = blk & 15;
    int bh   = blk >> 4;
    int b    = bh >> 4;
    int h    = bh & 15;
    int tid  = threadIdx.x;
    int wave = tid >> 6;
    int lane = tid & 63;
    int lq   = lane & 15;   // A-frag row / C-frag col
    int lg   = lane >> 4;   // group 0..3
    int r    = tid >> 2;    // staging row 0..63
    int c0   = (tid & 3) << 4;  // staging col base

    __shared__ __align__(16) u16 Kt[64][72];      // K tile [key][d]
    __shared__ __align__(16) u16 Vt[64][72];      // V^T tile [d][key]
    __shared__ __align__(16) u16 Ps[4][32][72];   // per-wave P tile [m][key]

    const u16* base  = qkv  + (size_t)bh * S_ * D_;
    const u16* baseT = qkvT + (size_t)bh * D_ * S_;
    int s0 = qt * 128;

    // Q A-fragments (2 row-frags), loaded once from global
    short8 aq[2][2];
#pragma unroll
    for (int rf = 0; rf < 2; rf++) {
        const u16* qrow = base + (size_t)(s0 + wave * 32 + rf * 16 + lq) * D_ + lg * 8;
        aq[rf][0] = *(const short8*)qrow;
        aq[rf][1] = *(const short8*)(qrow + 32);
    }

    floatx4 oacc[2][4] = {{{0,0,0,0},{0,0,0,0},{0,0,0,0},{0,0,0,0}},
                          {{0,0,0,0},{0,0,0,0},{0,0,0,0},{0,0,0,0}}};
    float lr[2][4] = {{0.f,0.f,0.f,0.f},{0.f,0.f,0.f,0.f}};

    for (int kt = 0; kt < S_ / 64; kt++) {
        __syncthreads();   // prev iteration's Kt/Vt reads complete
        {
            const u16* p = base + (size_t)(kt * 64 + r) * D_ + c0;
            *(uint4*)&Kt[r][c0]     = *(const uint4*)p;
            *(uint4*)&Kt[r][c0 + 8] = *(const uint4*)(p + 8);
            const u16* p2 = baseT + (size_t)r * S_ + kt * 64 + c0;
            *(uint4*)&Vt[r][c0]     = *(const uint4*)p2;
            *(uint4*)&Vt[r][c0 + 8] = *(const uint4*)(p2 + 8);
        }
        __syncthreads();

        // S = Q K^T : 4 key tiles x 2 row-frags; B-frags read once per tile
        floatx4 sc[2][4];
#pragma unroll
        for (int t = 0; t < 4; t++) {
            short8 b0 = *(short8*)&Kt[t * 16 + lq][lg * 8];
            short8 b1 = *(short8*)&Kt[t * 16 + lq][32 + lg * 8];
#pragma unroll
            for (int rf = 0; rf < 2; rf++) {
                floatx4 acc = {0, 0, 0, 0};
                acc = __builtin_amdgcn_mfma_f32_16x16x32_bf16(aq[rf][0], b0, acc, 0, 0, 0);
                sc[rf][t] = __builtin_amdgcn_mfma_f32_16x16x32_bf16(aq[rf][1], b1, acc, 0, 0, 0);
            }
        }

        // max-free softmax: p = exp2(s * EXP2_SCALE); lane-partial sums
#pragma unroll
        for (int rf = 0; rf < 2; rf++)
#pragma unroll
            for (int t = 0; t < 4; t++)
#pragma unroll
                for (int rr = 0; rr < 4; rr++) {
                    float p = exp2f(sc[rf][t][rr] * EXP2_SCALE);
                    sc[rf][t][rr] = p;
                    lr[rf][rr] += p;
                }

        // write P (C-layout) to per-wave LDS as [m][key] bf16
#pragma unroll
        for (int rf = 0; rf < 2; rf++)
#pragma unroll
            for (int t = 0; t < 4; t++)
#pragma unroll
                for (int rr = 0; rr < 4; rr++)
                    Ps[wave][rf * 16 + lg * 4 + rr][t * 16 + lq] = f2bf(sc[rf][t][rr]);

        // per-wave LDS: DS pipe in-order per wave; drain writes before reads
        asm volatile("s_waitcnt lgkmcnt(0)" ::: "memory");

        // O += P[32x64] * V[64x64]; V B-frags read once per tile
        short8 ap[2][2];
#pragma unroll
        for (int rf = 0; rf < 2; rf++) {
            ap[rf][0] = *(short8*)&Ps[wave][rf * 16 + lq][lg * 8];
            ap[rf][1] = *(short8*)&Ps[wave][rf * 16 + lq][32 + lg * 8];
        }
#pragma unroll
        for (int t = 0; t < 4; t++) {
            short8 bv0 = *(short8*)&Vt[t * 16 + lq][lg * 8];
            short8 bv1 = *(short8*)&Vt[t * 16 + lq][32 + lg * 8];
#pragma unroll
            for (int rf = 0; rf < 2; rf++) {
                oacc[rf][t] = __builtin_amdgcn_mfma_f32_16x16x32_bf16(ap[rf][0], bv0, oacc[rf][t], 0, 0, 0);
                oacc[rf][t] = __builtin_amdgcn_mfma_f32_16x16x32_bf16(ap[rf][1], bv1, oacc[rf][t], 0, 0, 0);
            }
        }
    }

    // reduce row sums across the 16 lanes holding each row, then normalize
#pragma unroll
    for (int rf = 0; rf < 2; rf++)
#pragma unroll
        for (int rr = 0; rr < 4; rr++) {
            lr[rf][rr] += __shfl_xor(lr[rf][rr], 1, 16);
            lr[rf][rr] += __shfl_xor(lr[rf][rr], 2, 16);
            lr[rf][rr] += __shfl_xor(lr[rf][rr], 4, 16);
            lr[rf][rr] += __shfl_xor(lr[rf][rr], 8, 16);
        }
#pragma unroll
    for (int rf = 0; rf < 2; rf++)
#pragma unroll
        for (int t = 0; t < 4; t++)
#pragma unroll
            for (int rr = 0; rr < 4; rr++) {
                float inv = 1.0f / fmaxf(lr[rf][rr], 1e-20f);
                int srow = s0 + wave * 32 + rf * 16 + lg * 4 + rr;
                int col  = h * D_ + t * 16 + lq;
                aout[((size_t)(b * S_ + srow)) * E_ + col] = f2bf(oacc[rf][t][rr] * inv);
            }
}

// ---------------------------------------------------------------------------
// Kernel 3: Wbf[i] = bf16(W[i])  — one-time weight conversion (1M elems)
// ---------------------------------------------------------------------------
__global__ __launch_bounds__(256) void wconv_kernel(const float* __restrict__ W,
                                                    u16* __restrict__ Wb) {
    int i = (blockIdx.x * 256 + threadIdx.x) * 4;
    float4 w = *(const float4*)(W + i);
    ushort4 o;
    o.x = f2bf(w.x); o.y = f2bf(w.y); o.z = f2bf(w.z); o.w = f2bf(w.w);
    *(ushort4*)(Wb + i) = o;
}

// ---------------------------------------------------------------------------
// Kernel 4: out[8192][1024] = AO * Wb^T + bias (fp32 out). Wb bf16 [n][k].
// 128x128 tile per block, 4 waves in 2x2, each wave 64x64 (4x4 C-tiles).
// ---------------------------------------------------------------------------
__global__ __launch_bounds__(256) void proj_kernel(const u16* __restrict__ A,
                                                   const u16* __restrict__ Wb,
                                                   const float* __restrict__ bias,
                                                   float* __restrict__ out) {
    int m0   = blockIdx.x * 128;
    int n0   = blockIdx.y * 128;
    int tid  = threadIdx.x;
    int wave = tid >> 6;
    int wm   = wave >> 1;
    int wn   = wave & 1;
    int lane = tid & 63;
    int lq   = lane & 15;
    int lg   = lane >> 4;
    int r    = tid >> 1;           // staging row 0..127
    int c0   = (tid & 1) * 32;     // staging col base {0,32}

    __shared__ __align__(16) u16 As[128][72];
    __shared__ __align__(16) u16 Bs[128][72];

    floatx4 acc[4][4];
#pragma unroll
    for (int i = 0; i < 4; i++)
#pragma unroll
        for (int j = 0; j < 4; j++) acc[i][j] = (floatx4){0, 0, 0, 0};

    for (int kc = 0; kc < E_; kc += 64) {
        __syncthreads();
        const u16* pa = A + (size_t)(m0 + r) * E_ + kc + c0;
        const u16* pw = Wb + (size_t)(n0 + r) * E_ + kc + c0;
#pragma unroll
        for (int j = 0; j < 4; j++) {
            *(uint4*)&As[r][c0 + j * 8] = *(const uint4*)(pa + j * 8);
            *(uint4*)&Bs[r][c0 + j * 8] = *(const uint4*)(pw + j * 8);
        }
        __syncthreads();

#pragma unroll
        for (int c = 0; c < 2; c++) {
            short8 af[4], bf[4];
#pragma unroll
            for (int i = 0; i < 4; i++)
                af[i] = *(short8*)&As[wm * 64 + i * 16 + lq][c * 32 + lg * 8];
#pragma unroll
            for (int j = 0; j < 4; j++)
                bf[j] = *(short8*)&Bs[wn * 64 + j * 16 + lq][c * 32 + lg * 8];
#pragma unroll
            for (int i = 0; i < 4; i++)
#pragma unroll
                for (int j = 0; j < 4; j++)
                    acc[i][j] = __builtin_amdgcn_mfma_f32_16x16x32_bf16(af[i], bf[j], acc[i][j], 0, 0, 0);
        }
    }

#pragma unroll
    for (int j = 0; j < 4; j++) {
        int nidx = n0 + wn * 64 + j * 16 + lq;
        float bv = bias[nidx];
#pragma unroll
        for (int i = 0; i < 4; i++) {
#pragma unroll
            for (int rr = 0; rr < 4; rr++) {
                int row = m0 + wm * 64 + i * 16 + lg * 4 + rr;
                out[(size_t)row * E_ + nidx] = acc[i][j][rr] + bv;
            }
        }
    }
}

// ---------------------------------------------------------------------------
extern "C" void kernel_launch(void* const* d_in, const int* in_sizes, int n_in,
                              void* d_out, int out_size, void* d_ws, size_t ws_size,
                              hipStream_t stream) {
    const float* x     = (const float*)d_in[0];
    const float* theta = (const float*)d_in[1];
    const float* w_out = (const float*)d_in[2];
    const float* b_out = (const float*)d_in[3];
    float* out = (float*)d_out;

    char* ws = (char*)d_ws;
    const size_t QKV_BYTES = (size_t)B_ * H_ * S_ * D_ * sizeof(u16);  // 16 MiB
    u16* qkv  = (u16*)ws;
    u16* qkvT = (u16*)(ws + QKV_BYTES);
    u16* aout = (u16*)(ws + 2 * QKV_BYTES);
    u16* wbf  = (u16*)ws;   // reuses qkv region AFTER attn completes (stream-ordered)

    qkv_kernel<<<(B_ * H_) * (S_ / 64), 256, 0, stream>>>(x, theta, qkv, qkvT);
    attn_kernel<<<(B_ * H_) * (S_ / 128), 256, 0, stream>>>(qkv, qkvT, aout);
    wconv_kernel<<<(E_ * E_) / 1024, 256, 0, stream>>>(w_out, wbf);
    dim3 pg(B_ * S_ / 128, E_ / 128);
    proj_kernel<<<pg, 256, 0, stream>>>(aout, wbf, b_out, out);
}

// Round 8
// 203.265 us; speedup vs baseline: 2.9382x; 1.1885x over previous
//
#include <hip/hip_runtime.h>

// Problem: B=4, S=2048, H=16, D=64, E=1024. Inputs fp32, output fp32.
// out = proj( attention( cos(x+theta) ) )  with Q==K==V per head.
//
// Round 8: S^T formulation. QK^T computed operand-swapped => each lane owns
// ONE q and 16 consecutive-key values => P packs with v_perm (bf16-trunc)
// into ds_write_b64, PV reads P^T B-frags as ds_read_b128. Scale*log2e
// folded into pre-scaled Q B-frags. qkv+wconv fused into one prep kernel.
// ws: [0,16M) qkv (reused as Wbf)  [16M,32M) qkvT  [32M,48M) aout.

#define B_  4
#define S_  2048
#define H_  16
#define D_  64
#define E_  1024
// exp(s/8) = exp2(s * log2(e)/8); folded into Q fragments
#define EXP2_SCALE 0.18033688011112043f

typedef unsigned short u16;
typedef unsigned int u32;
typedef __attribute__((ext_vector_type(8))) short short8;
typedef __attribute__((ext_vector_type(4))) float floatx4;

static __device__ __forceinline__ float bf2f(u16 v) {
    return __uint_as_float(((unsigned)v) << 16);
}
static __device__ __forceinline__ u16 f2bf(float f) {
    unsigned u = __float_as_uint(f);
    return (u16)((u + 0x7FFFu + ((u >> 16) & 1u)) >> 16);
}
// pack bf16(lo),bf16(hi) from two f32 by truncation: 1 v_perm_b32
static __device__ __forceinline__ u32 pack_bf16_trunc(float lo, float hi) {
    return __builtin_amdgcn_perm(__float_as_uint(hi), __float_as_uint(lo), 0x07060302u);
}
// unpack-scale-repack a short8 of bf16 by EXP2_SCALE (one-time, RNE)
static __device__ __forceinline__ short8 scale8(short8 v) {
    short8 o;
#pragma unroll
    for (int i = 0; i < 8; i++)
        o[i] = (short)f2bf(bf2f((u16)v[i]) * EXP2_SCALE);
    return o;
}

// ---------------------------------------------------------------------------
// Kernel 1 (fused prep):
//  blocks [0,2048):   qkv[bh][s][d] = cos(x+theta) bf16, qkvT = transpose
//  blocks [2048,3072): Wbf = bf16(W)
// ---------------------------------------------------------------------------
__global__ __launch_bounds__(256) void prep_kernel(const float* __restrict__ x,
                                                   const float* __restrict__ theta,
                                                   const float* __restrict__ W,
                                                   u16* __restrict__ qkv,
                                                   u16* __restrict__ qkvT,
                                                   u16* __restrict__ Wb) {
    __shared__ __align__(16) u16 TQ[64][72];
    int blk = blockIdx.x;
    int tid = threadIdx.x;
    if (blk >= 2048) {  // wconv part
        int i = ((blk - 2048) * 256 + tid) * 4;
        float4 w = *(const float4*)(W + i);
        ushort4 o;
        o.x = f2bf(w.x); o.y = f2bf(w.y); o.z = f2bf(w.z); o.w = f2bf(w.w);
        *(ushort4*)(Wb + i) = o;
        return;
    }
    int stile = blk & 31;
    int bh    = blk >> 5;
    int b     = bh >> 4;
    int h     = bh & 15;
    int i     = tid >> 2;
    int d0    = (tid & 3) << 4;
    int s0    = stile << 6;
    int s     = s0 + i;

    const float* xp = x + ((size_t)(b * S_ + s)) * E_ + h * D_ + d0;
    const float* tp = theta + h * D_ + d0;

    u16 ov[16];
#pragma unroll
    for (int j = 0; j < 16; j += 4) {
        float4 xv = *(const float4*)(xp + j);
        float4 tv = *(const float4*)(tp + j);
        ov[j]     = f2bf(__cosf(xv.x + tv.x));
        ov[j + 1] = f2bf(__cosf(xv.y + tv.y));
        ov[j + 2] = f2bf(__cosf(xv.z + tv.z));
        ov[j + 3] = f2bf(__cosf(xv.w + tv.w));
    }

    u16* qp = qkv + ((size_t)bh * S_ + s) * D_ + d0;
    *(uint4*)qp       = *(uint4*)&ov[0];
    *(uint4*)(qp + 8) = *(uint4*)&ov[8];

#pragma unroll
    for (int j = 0; j < 16; j++) TQ[d0 + j][i] = ov[j];
    __syncthreads();

    int d  = tid >> 2;
    int j0 = (tid & 3) << 4;
    u16 tmp[16];
#pragma unroll
    for (int j = 0; j < 16; j++) tmp[j] = TQ[d][j0 + j];
    u16* qtp = qkvT + ((size_t)bh * D_ + d) * S_ + s0 + j0;
    *(uint4*)qtp       = *(uint4*)&tmp[0];
    *(uint4*)(qtp + 8) = *(uint4*)&tmp[8];
}

// ---------------------------------------------------------------------------
// Kernel 2: flash attention per (bh, 128-q-tile), S^T formulation.
// 4 waves; wave w owns q rows [w*32,w*32+32) as rf=0,1 (16 q each = B-frag n).
// QK^T: mfma(K_frag, Qs_frag) -> S^T: lane owns q=lq, keys 16t+4lg+rr.
// P packed (v_perm trunc) -> Pb[q][key] b64 writes -> PV B-frag b128 reads.
// PV: mfma(Vt_frag, Pb_frag) -> O^T: lane owns q=lq, d=16t+4lg+rr.
// ---------------------------------------------------------------------------
__global__ __launch_bounds__(256, 4) void attn_kernel(const u16* __restrict__ qkv,
                                                      const u16* __restrict__ qkvT,
                                                      u16* __restrict__ aout) {
    int blk  = blockIdx.x;
    int qt   = blk & 15;
    int bh   = blk >> 4;
    int b    = bh >> 4;
    int h    = bh & 15;
    int tid  = threadIdx.x;
    int wave = tid >> 6;
    int lane = tid & 63;
    int lq   = lane & 15;   // frag row/col index; here: this lane's q (and key row for A)
    int lg   = lane >> 4;   // quad 0..3
    int r    = tid >> 2;    // staging row 0..63
    int c0   = (tid & 3) << 4;

    __shared__ __align__(16) u16 Kt[64][72];      // K tile [key][d]
    __shared__ __align__(16) u16 Vt[64][72];      // V^T tile [d][key]
    __shared__ __align__(16) u16 Pb[4][32][72];   // per-wave P [q=rf*16+lq][key]

    const u16* base  = qkv  + (size_t)bh * S_ * D_;
    const u16* baseT = qkvT + (size_t)bh * D_ * S_;
    int s0 = qt * 128;

    // Q B-frags (pre-scaled by EXP2_SCALE), loaded once. B[k=d=lg*8+j][n=q=lq]
    short8 bq[2][2];
#pragma unroll
    for (int rf = 0; rf < 2; rf++) {
        const u16* qrow = base + (size_t)(s0 + wave * 32 + rf * 16 + lq) * D_ + lg * 8;
        bq[rf][0] = scale8(*(const short8*)qrow);
        bq[rf][1] = scale8(*(const short8*)(qrow + 32));
    }

    floatx4 oacc[2][4] = {{{0,0,0,0},{0,0,0,0},{0,0,0,0},{0,0,0,0}},
                          {{0,0,0,0},{0,0,0,0},{0,0,0,0},{0,0,0,0}}};
    float lsum[2] = {0.f, 0.f};

    for (int kt = 0; kt < S_ / 64; kt++) {
        __syncthreads();
        {
            const u16* p = base + (size_t)(kt * 64 + r) * D_ + c0;
            *(uint4*)&Kt[r][c0]     = *(const uint4*)p;
            *(uint4*)&Kt[r][c0 + 8] = *(const uint4*)(p + 8);
            const u16* p2 = baseT + (size_t)r * S_ + kt * 64 + c0;
            *(uint4*)&Vt[r][c0]     = *(const uint4*)p2;
            *(uint4*)&Vt[r][c0 + 8] = *(const uint4*)(p2 + 8);
        }
        __syncthreads();

        // S^T tiles: A = K-frag A[m=key=lq][k=d], B = bq. sc[rf][t][rr]:
        // value at key = 16t+4lg+rr, q = lq (already ×EXP2_SCALE)
        floatx4 sc[2][4];
#pragma unroll
        for (int t = 0; t < 4; t++) {
            short8 a0 = *(short8*)&Kt[t * 16 + lq][lg * 8];
            short8 a1 = *(short8*)&Kt[t * 16 + lq][32 + lg * 8];
#pragma unroll
            for (int rf = 0; rf < 2; rf++) {
                floatx4 acc = {0, 0, 0, 0};
                acc = __builtin_amdgcn_mfma_f32_16x16x32_bf16(a0, bq[rf][0], acc, 0, 0, 0);
                sc[rf][t] = __builtin_amdgcn_mfma_f32_16x16x32_bf16(a1, bq[rf][1], acc, 0, 0, 0);
            }
        }

        // p = exp2(sc); lane-scalar lsum; pack pairs; b64 store to Pb[q][key]
#pragma unroll
        for (int rf = 0; rf < 2; rf++) {
#pragma unroll
            for (int t = 0; t < 4; t++) {
                float p0 = __builtin_amdgcn_exp2f(sc[rf][t][0]);
                float p1 = __builtin_amdgcn_exp2f(sc[rf][t][1]);
                float p2 = __builtin_amdgcn_exp2f(sc[rf][t][2]);
                float p3 = __builtin_amdgcn_exp2f(sc[rf][t][3]);
                lsum[rf] += (p0 + p1) + (p2 + p3);
                uint2 w;
                w.x = pack_bf16_trunc(p0, p1);
                w.y = pack_bf16_trunc(p2, p3);
                *(uint2*)&Pb[wave][rf * 16 + lq][t * 16 + lg * 4] = w;
            }
        }

        // per-wave DS in-order: drain writes before dependent reads
        asm volatile("s_waitcnt lgkmcnt(0)" ::: "memory");

        // O^T += V^T · P^T : A = Vt rows (d), B = Pb rows (q)
        short8 bp[2][2];
#pragma unroll
        for (int rf = 0; rf < 2; rf++) {
            bp[rf][0] = *(short8*)&Pb[wave][rf * 16 + lq][lg * 8];
            bp[rf][1] = *(short8*)&Pb[wave][rf * 16 + lq][32 + lg * 8];
        }
#pragma unroll
        for (int t = 0; t < 4; t++) {
            short8 av0 = *(short8*)&Vt[t * 16 + lq][lg * 8];
            short8 av1 = *(short8*)&Vt[t * 16 + lq][32 + lg * 8];
#pragma unroll
            for (int rf = 0; rf < 2; rf++) {
                oacc[rf][t] = __builtin_amdgcn_mfma_f32_16x16x32_bf16(av0, bp[rf][0], oacc[rf][t], 0, 0, 0);
                oacc[rf][t] = __builtin_amdgcn_mfma_f32_16x16x32_bf16(av1, bp[rf][1], oacc[rf][t], 0, 0, 0);
            }
        }
    }

    // reduce lsum across the 4 lane-quads holding the same q
#pragma unroll
    for (int rf = 0; rf < 2; rf++) {
        lsum[rf] += __shfl_xor(lsum[rf], 16);
        lsum[rf] += __shfl_xor(lsum[rf], 32);
    }
    // epilogue: O^T lane (q=lq, d=16t+4lg+rr) -> aout[b][q][h*64+d] (RNE)
#pragma unroll
    for (int rf = 0; rf < 2; rf++) {
        float inv = 1.0f / fmaxf(lsum[rf], 1e-20f);
        int srow = s0 + wave * 32 + rf * 16 + lq;
        u16* arow = aout + ((size_t)(b * S_ + srow)) * E_ + h * D_;
#pragma unroll
        for (int t = 0; t < 4; t++)
#pragma unroll
            for (int rr = 0; rr < 4; rr++)
                arow[t * 16 + lg * 4 + rr] = f2bf(oacc[rf][t][rr] * inv);
    }
}

// ---------------------------------------------------------------------------
// Kernel 3: out[8192][1024] = AO * Wb^T + bias (fp32 out). Wb bf16 [n][k].
// 128x128 tile per block, 4 waves in 2x2, each wave 64x64 (4x4 C-tiles).
// ---------------------------------------------------------------------------
__global__ __launch_bounds__(256) void proj_kernel(const u16* __restrict__ A,
                                                   const u16* __restrict__ Wb,
                                                   const float* __restrict__ bias,
                                                   float* __restrict__ out) {
    int m0   = blockIdx.x * 128;
    int n0   = blockIdx.y * 128;
    int tid  = threadIdx.x;
    int wave = tid >> 6;
    int wm   = wave >> 1;
    int wn   = wave & 1;
    int lane = tid & 63;
    int lq   = lane & 15;
    int lg   = lane >> 4;
    int r    = tid >> 1;
    int c0   = (tid & 1) * 32;

    __shared__ __align__(16) u16 As[128][72];
    __shared__ __align__(16) u16 Bs[128][72];

    floatx4 acc[4][4];
#pragma unroll
    for (int i = 0; i < 4; i++)
#pragma unroll
        for (int j = 0; j < 4; j++) acc[i][j] = (floatx4){0, 0, 0, 0};

    for (int kc = 0; kc < E_; kc += 64) {
        __syncthreads();
        const u16* pa = A + (size_t)(m0 + r) * E_ + kc + c0;
        const u16* pw = Wb + (size_t)(n0 + r) * E_ + kc + c0;
#pragma unroll
        for (int j = 0; j < 4; j++) {
            *(uint4*)&As[r][c0 + j * 8] = *(const uint4*)(pa + j * 8);
            *(uint4*)&Bs[r][c0 + j * 8] = *(const uint4*)(pw + j * 8);
        }
        __syncthreads();

#pragma unroll
        for (int c = 0; c < 2; c++) {
            short8 af[4], bf[4];
#pragma unroll
            for (int i = 0; i < 4; i++)
                af[i] = *(short8*)&As[wm * 64 + i * 16 + lq][c * 32 + lg * 8];
#pragma unroll
            for (int j = 0; j < 4; j++)
                bf[j] = *(short8*)&Bs[wn * 64 + j * 16 + lq][c * 32 + lg * 8];
#pragma unroll
            for (int i = 0; i < 4; i++)
#pragma unroll
                for (int j = 0; j < 4; j++)
                    acc[i][j] = __builtin_amdgcn_mfma_f32_16x16x32_bf16(af[i], bf[j], acc[i][j], 0, 0, 0);
        }
    }

#pragma unroll
    for (int j = 0; j < 4; j++) {
        int nidx = n0 + wn * 64 + j * 16 + lq;
        float bv = bias[nidx];
#pragma unroll
        for (int i = 0; i < 4; i++) {
#pragma unroll
            for (int rr = 0; rr < 4; rr++) {
                int row = m0 + wm * 64 + i * 16 + lg * 4 + rr;
                out[(size_t)row * E_ + nidx] = acc[i][j][rr] + bv;
            }
        }
    }
}

// ---------------------------------------------------------------------------
extern "C" void kernel_launch(void* const* d_in, const int* in_sizes, int n_in,
                              void* d_out, int out_size, void* d_ws, size_t ws_size,
                              hipStream_t stream) {
    const float* x     = (const float*)d_in[0];
    const float* theta = (const float*)d_in[1];
    const float* w_out = (const float*)d_in[2];
    const float* b_out = (const float*)d_in[3];
    float* out = (float*)d_out;

    char* ws = (char*)d_ws;
    const size_t QKV_BYTES = (size_t)B_ * H_ * S_ * D_ * sizeof(u16);  // 16 MiB
    u16* qkv  = (u16*)ws;
    u16* qkvT = (u16*)(ws + QKV_BYTES);
    u16* aout = (u16*)(ws + 2 * QKV_BYTES);
    u16* wbf  = (u16*)ws;   // NOTE: wconv blocks in prep may run before/with qkv
                            // blocks — but they touch DISJOINT regions? No:
                            // wbf aliases qkv! Must NOT alias. Use aout+16M? No.
    // Fix: place wbf in its own region beyond aout (ws >= 64M assumed false).
    // Safe alternative: wbf overwrites qkv only AFTER attn. Since prep fuses
    // them, give wconv its own slice: reuse qkvT? also live. -> Put wbf at
    // [48M,50M) if ws allows; else fall back to separate launch ordering.
    // We keep it simple and CORRECT: wbf gets [48M, 50M).
    u16* wbf_safe = (u16*)(ws + 3 * QKV_BYTES);

    prep_kernel<<<3072, 256, 0, stream>>>(x, theta, w_out, qkv, qkvT, wbf_safe);
    attn_kernel<<<(B_ * H_) * (S_ / 128), 256, 0, stream>>>(qkv, qkvT, aout);
    dim3 pg(B_ * S_ / 128, E_ / 128);
    proj_kernel<<<pg, 256, 0, stream>>>(aout, wbf_safe, b_out, out);
    (void)wbf;
}